// Round 1
// baseline (649.873 us; speedup 1.0000x reference)
//
#include <hip/hip_runtime.h>

#define LSEQ 8192
#define MFFT 16384      // 2*L, = 4^7
#define NTHREADS 1024
#define CCH 2048

__device__ __forceinline__ unsigned rev4_14(unsigned x) {
    // reverse 7 base-4 digits of a 14-bit number
    unsigned r = __brev(x) >> 18;                                  // bit-reverse low 14
    return ((r & 0x2AAAu) >> 1) | ((r & 0x1555u) << 1);            // swap adjacent bit pairs
}

__global__ __launch_bounds__(NTHREADS)
void hyena_fftconv(const float* __restrict__ x,
                   const float* __restrict__ k,
                   const float* __restrict__ bias,
                   float* __restrict__ y)
{
    __shared__ float2 d[MFFT];   // 128 KiB

    const int bc  = blockIdx.x;          // b*C + c
    const int c   = bc & (CCH - 1);
    const int tid = threadIdx.x;

    const float* xp = x + (size_t)bc * LSEQ;
    const float* kp = k + (size_t)c  * LSEQ;
    float*       yp = y + (size_t)bc * LSEQ;
    const float  bc0 = bias[c];

    // ---- load & pack: d[m] = x_pad[m] + i * k_pad[m]; bias folds into k[0] ----
    for (int m = tid; m < LSEQ; m += NTHREADS) {
        float xv = xp[m];
        float kv = kp[m];
        if (m == 0) kv += bc0;           // bias[c]*x == conv tap at s=0
        d[m] = make_float2(xv, kv);
    }
    for (int m = LSEQ + tid; m < MFFT; m += NTHREADS)
        d[m] = make_float2(0.f, 0.f);
    __syncthreads();

    // ---- forward radix-4 DIF (natural in -> digit-reversed out), e^{-i} ----
    for (int q = MFFT / 4; q >= 1; q >>= 2) {
        const float thbase = -1.5707963267948966f / (float)q;   // -(pi/2)/q
        for (int bf = tid; bf < MFFT / 4; bf += NTHREADS) {
            int i    = bf & (q - 1);
            int base = ((bf - i) << 2) + i;       // (bf/q)*4q + i
            float2 a0 = d[base], a1 = d[base + q], a2 = d[base + 2*q], a3 = d[base + 3*q];

            float t0r = a0.x + a2.x, t0i = a0.y + a2.y;
            float t1r = a0.x - a2.x, t1i = a0.y - a2.y;
            float t2r = a1.x + a3.x, t2i = a1.y + a3.y;
            float t3r = a1.x - a3.x, t3i = a1.y - a3.y;

            float b0r = t0r + t2r, b0i = t0i + t2i;
            float b1r = t1r + t3i, b1i = t1i - t3r;   // t1 - i*t3
            float b2r = t0r - t2r, b2i = t0i - t2i;
            float b3r = t1r - t3i, b3i = t1i + t3r;   // t1 + i*t3

            float th = thbase * (float)i;
            float s1, c1;
            __sincosf(th, &s1, &c1);
            float c2 = c1 * c1 - s1 * s1, s2 = 2.f * c1 * s1;
            float c3 = c1 * c2 - s1 * s2, s3 = s1 * c2 + c1 * s2;

            d[base]         = make_float2(b0r, b0i);
            d[base + q]     = make_float2(b1r * c1 - b1i * s1, b1r * s1 + b1i * c1);
            d[base + 2*q]   = make_float2(b2r * c2 - b2i * s2, b2r * s2 + b2i * c2);
            d[base + 3*q]   = make_float2(b3r * c3 - b3i * s3, b3r * s3 + b3i * c3);
        }
        __syncthreads();
    }

    // ---- pointwise multiply in digit-reversed space ----
    // X[j]*K[j] = (-i/4)*(C[j]^2 - conj(C[M-j])^2);  write W = X*K/M (Hermitian)
    {
        const float s = 1.0f / (4.0f * (float)MFFT);
        for (int j = tid; j <= MFFT / 2; j += NTHREADS) {
            unsigned pj = rev4_14((unsigned)j);
            unsigned pk = rev4_14((unsigned)((MFFT - j) & (MFFT - 1)));
            float2 Ca = d[pj], Cb = d[pk];
            float ar = Ca.x * Ca.x - Ca.y * Ca.y, ai = 2.f * Ca.x * Ca.y;  // Ca^2
            float br = Cb.x * Cb.x - Cb.y * Cb.y, bi = 2.f * Cb.x * Cb.y;  // Cb^2
            float wr = s * (ai + bi);
            float wi = s * (br - ar);
            d[pj] = make_float2(wr,  wi);
            d[pk] = make_float2(wr, -wi);
        }
    }
    __syncthreads();

    // ---- inverse radix-4 DIT (digit-reversed in -> natural out), e^{+i}, unscaled ----
    for (int q = 1; q <= MFFT / 4; q <<= 2) {
        const float thbase = 1.5707963267948966f / (float)q;    // +(pi/2)/q
        for (int bf = tid; bf < MFFT / 4; bf += NTHREADS) {
            int i    = bf & (q - 1);
            int base = ((bf - i) << 2) + i;
            float2 v0 = d[base], v1 = d[base + q], v2 = d[base + 2*q], v3 = d[base + 3*q];

            float th = thbase * (float)i;
            float s1, c1;
            __sincosf(th, &s1, &c1);
            float c2 = c1 * c1 - s1 * s1, s2 = 2.f * c1 * s1;
            float c3 = c1 * c2 - s1 * s2, s3 = s1 * c2 + c1 * s2;

            float a0r = v0.x,                  a0i = v0.y;
            float a1r = v1.x * c1 - v1.y * s1, a1i = v1.x * s1 + v1.y * c1;
            float a2r = v2.x * c2 - v2.y * s2, a2i = v2.x * s2 + v2.y * c2;
            float a3r = v3.x * c3 - v3.y * s3, a3i = v3.x * s3 + v3.y * c3;

            float u0r = a0r + a2r, u0i = a0i + a2i;
            float u1r = a0r - a2r, u1i = a0i - a2i;
            float u2r = a1r + a3r, u2i = a1i + a3i;
            float u3r = a1r - a3r, u3i = a1i - a3i;

            d[base]         = make_float2(u0r + u2r, u0i + u2i);
            d[base + q]     = make_float2(u1r - u3i, u1i + u3r);  // u1 + i*u3
            d[base + 2*q]   = make_float2(u0r - u2r, u0i - u2i);
            d[base + 3*q]   = make_float2(u1r + u3i, u1i - u3r);  // u1 - i*u3
        }
        __syncthreads();
    }

    // ---- write y = Re(w[0..L-1]) ----
    for (int t = tid; t < LSEQ; t += NTHREADS)
        yp[t] = d[t].x;
}

extern "C" void kernel_launch(void* const* d_in, const int* in_sizes, int n_in,
                              void* d_out, int out_size, void* d_ws, size_t ws_size,
                              hipStream_t stream) {
    const float* x    = (const float*)d_in[0];
    const float* k    = (const float*)d_in[1];
    const float* bias = (const float*)d_in[2];
    float* y          = (float*)d_out;

    const int B = 2;
    const int nblocks = B * CCH;   // 4096 blocks, one per (b, c)
    hyena_fftconv<<<dim3(nblocks), dim3(NTHREADS), 0, stream>>>(x, k, bias, y);
}

// Round 2
// 303.220 us; speedup vs baseline: 2.1432x; 2.1432x over previous
//
#include <hip/hip_runtime.h>

#define LSEQ 8192
#define MFFT 16384      // 2*L = 16^3 * 4
#define NT 1024
#define CCH 2048

// XOR bank swizzle: conflict-free for all pass access patterns (verified per
// quarter-wave: slot%16 is a permutation of 0..15 for every read/write phase).
__device__ __forceinline__ int SL(int i) { return i ^ ((i >> 4) & 15); }

__device__ __forceinline__ float2 cmul(float2 a, float2 b) {
    return make_float2(fmaf(a.x, b.x, -a.y * b.y), fmaf(a.x, b.y, a.y * b.x));
}

// In-place radix-4 DFT: inputs x[n], outputs X[k] in same slots. W4 = e^{SGN*2pi i/4}.
template<int SGN>
__device__ __forceinline__ void dft4(float2& a0, float2& a1, float2& a2, float2& a3) {
    float t0x = a0.x + a2.x, t0y = a0.y + a2.y;
    float t1x = a0.x - a2.x, t1y = a0.y - a2.y;
    float t2x = a1.x + a3.x, t2y = a1.y + a3.y;
    float t3x = a1.x - a3.x, t3y = a1.y - a3.y;
    // u = SGN * i * t3
    float ux = (SGN < 0) ? t3y : -t3y;
    float uy = (SGN < 0) ? -t3x : t3x;
    a0 = make_float2(t0x + t2x, t0y + t2y);
    a1 = make_float2(t1x + ux, t1y + uy);
    a2 = make_float2(t0x - t2x, t0y - t2y);
    a3 = make_float2(t1x - ux, t1y - uy);
}

// Radix-16 DFT on registers, natural in, natural out: X[k] ends at v[4*(k&3)+(k>>2)].
template<int SGN>
__device__ __forceinline__ void dft16(float2 v[16]) {
    dft4<SGN>(v[0], v[4], v[8],  v[12]);
    dft4<SGN>(v[1], v[5], v[9],  v[13]);
    dft4<SGN>(v[2], v[6], v[10], v[14]);
    dft4<SGN>(v[3], v[7], v[11], v[15]);
    const float sg = (float)SGN;
    const float C1 = 0.92387953251f, S1 = 0.38268343236f, C2 = 0.70710678119f;
    const float2 w1 = make_float2( C1,  sg * S1);
    const float2 w2 = make_float2( C2,  sg * C2);
    const float2 w3 = make_float2( S1,  sg * C1);
    const float2 w6 = make_float2(-C2,  sg * C2);
    const float2 w9 = make_float2(-C1, -sg * S1);
    v[5]  = cmul(v[5],  w1);
    v[6]  = cmul(v[6],  w2);
    v[7]  = cmul(v[7],  w3);
    v[9]  = cmul(v[9],  w2);
    v[10] = make_float2(-sg * v[10].y, sg * v[10].x);   // *W16^4 = (0, sg)
    v[11] = cmul(v[11], w6);
    v[13] = cmul(v[13], w3);
    v[14] = cmul(v[14], w6);
    v[15] = cmul(v[15], w9);
    dft4<SGN>(v[0],  v[1],  v[2],  v[3]);
    dft4<SGN>(v[4],  v[5],  v[6],  v[7]);
    dft4<SGN>(v[8],  v[9],  v[10], v[11]);
    dft4<SGN>(v[12], v[13], v[14], v[15]);
}

// One Stockham radix-16 pass. Caller guarantees LDS is consistent on entry.
// reads -> (compute) -> barrier -> scatter writes -> barrier.
template<int SGN, int NS>
__device__ __forceinline__ void pass16(float2* ds, int tid) {
    const int j = tid;                       // butterfly id in [0, MFFT/16)
    float2 v[16];
#pragma unroll
    for (int r = 0; r < 16; r++) v[r] = ds[SL(j + (r << 10))];   // stride N/R = 1024

    if constexpr (NS > 1) {
        const float kang = (float)SGN * 6.283185307179586f / (float)(NS * 16);
        float ang = kang * (float)(j & (NS - 1));
        float s1, c1;
        __sincosf(ang, &s1, &c1);
        float2 wstep = make_float2(c1, s1);
        float2 w = wstep;
        v[1] = cmul(v[1], w);
#pragma unroll
        for (int r = 2; r < 16; r++) { w = cmul(w, wstep); v[r] = cmul(v[r], w); }
    }

    dft16<SGN>(v);
    __syncthreads();

    const int idxD = ((j & ~(NS - 1)) << 4) | (j & (NS - 1));
#pragma unroll
    for (int kk = 0; kk < 16; kk++)
        ds[SL(idxD + kk * NS)] = v[4 * (kk & 3) + (kk >> 2)];
    __syncthreads();
}

// Final radix-4 pass (NS = 4096): every thread's read/write index set is its own
// residue class mod 1024 -> race-free in place, no internal barrier needed.
template<int SGN>
__device__ __forceinline__ void pass4(float2* ds, int tid) {
    const float kang = (float)SGN * 6.283185307179586f / (float)MFFT;
#pragma unroll
    for (int b = 0; b < 4; b++) {
        int j = tid + (b << 10);
        float2 a0 = ds[SL(j)];
        float2 a1 = ds[SL(j + 4096)];
        float2 a2 = ds[SL(j + 8192)];
        float2 a3 = ds[SL(j + 12288)];
        float s1, c1;
        __sincosf(kang * (float)j, &s1, &c1);
        float2 w1 = make_float2(c1, s1);
        float2 w2 = cmul(w1, w1);
        float2 w3 = cmul(w2, w1);
        a1 = cmul(a1, w1);
        a2 = cmul(a2, w2);
        a3 = cmul(a3, w3);
        dft4<SGN>(a0, a1, a2, a3);
        ds[SL(j)]         = a0;
        ds[SL(j + 4096)]  = a1;
        ds[SL(j + 8192)]  = a2;
        ds[SL(j + 12288)] = a3;
    }
}

__global__ __launch_bounds__(NT)
void hyena_fftconv(const float* __restrict__ x,
                   const float* __restrict__ k,
                   const float* __restrict__ bias,
                   float* __restrict__ y)
{
    __shared__ float2 ds[MFFT];              // 128 KiB

    const int bc  = blockIdx.x;              // b*C + c
    const int c   = bc & (CCH - 1);
    const int tid = threadIdx.x;

    const float* xp = x + (size_t)bc * LSEQ;
    const float* kp = k + (size_t)c  * LSEQ;
    float*       yp = y + (size_t)bc * LSEQ;
    const float  b0 = bias[c];

    // load & pack: ds[m] = x[m] + i*k[m]; bias folds into k[0] (s=0 conv tap)
#pragma unroll
    for (int s = 0; s < 8; s++) {
        int m = tid + (s << 10);
        float xv = xp[m];
        float kv = kp[m];
        if (m == 0) kv += b0;
        ds[SL(m)] = make_float2(xv, kv);
    }
#pragma unroll
    for (int s = 0; s < 8; s++) {
        int m = LSEQ + tid + (s << 10);
        ds[SL(m)] = make_float2(0.f, 0.f);
    }
    __syncthreads();

    // forward FFT (natural -> natural, Stockham)
    pass16<-1, 1>(ds, tid);
    pass16<-1, 16>(ds, tid);
    pass16<-1, 256>(ds, tid);
    pass4<-1>(ds, tid);
    __syncthreads();

    // pointwise: X[j]*K[j] = -i/4 * (C[j]^2 - conj(C[M-j])^2), scaled by 1/M.
    // Pair (j, M-j) owned by one thread -> race-free, no barrier inside.
    {
        const float sc = 1.0f / (4.0f * (float)MFFT);
#pragma unroll
        for (int s = 0; s < 8; s++) {
            int j  = tid + (s << 10);                 // 0..8191, each once
            int jm = (MFFT - j) & (MFFT - 1);
            float2 Ca = ds[SL(j)];
            float2 Cb = ds[SL(jm)];
            float ar = Ca.x * Ca.x - Ca.y * Ca.y, ai = 2.f * Ca.x * Ca.y;
            float br = Cb.x * Cb.x - Cb.y * Cb.y, bi = 2.f * Cb.x * Cb.y;
            float wr = sc * (ai + bi);
            float wi = sc * (br - ar);
            ds[SL(j)]  = make_float2(wr,  wi);
            ds[SL(jm)] = make_float2(wr, -wi);
        }
        if (tid == 0) {                               // bin j = M/2 (self-paired)
            float2 Ca = ds[SL(8192)];
            float ai = 2.f * Ca.x * Ca.y;
            ds[SL(8192)] = make_float2(sc * 2.f * ai * 0.5f + sc * ai * 0.f + sc * (ai + ai) * 0.f + sc * (ai + ai), 0.f);
        }
    }
    __syncthreads();

    // inverse FFT (unscaled; 1/M folded into sc above)
    pass16<1, 1>(ds, tid);
    pass16<1, 16>(ds, tid);
    pass16<1, 256>(ds, tid);
    pass4<1>(ds, tid);
    __syncthreads();

    // y = Re(w[0..L-1])
#pragma unroll
    for (int s = 0; s < 8; s++) {
        int t = tid + (s << 10);
        yp[t] = ds[SL(t)].x;
    }
}

extern "C" void kernel_launch(void* const* d_in, const int* in_sizes, int n_in,
                              void* d_out, int out_size, void* d_ws, size_t ws_size,
                              hipStream_t stream) {
    const float* x    = (const float*)d_in[0];
    const float* k    = (const float*)d_in[1];
    const float* bias = (const float*)d_in[2];
    float* y          = (float*)d_out;

    const int B = 2;
    const int nblocks = B * CCH;   // 4096 blocks, one per (b, c)
    hyena_fftconv<<<dim3(nblocks), dim3(NT), 0, stream>>>(x, k, bias, y);
}